// Round 4
// baseline (309.171 us; speedup 1.0000x reference)
//
#include <hip/hip_runtime.h>
#include <hip/hip_bf16.h>
#include <cstdint>
#include <cstddef>

// Problem constants (fixed by the reference: anchor/positive [4096,512] f32, labels [4096] i32)
constexpr int BN = 4096;   // batch
constexpr int DN = 512;    // feature dim
constexpr int TN = 64;                    // tile edge (64x64 -> 2080 blocks ~ 8/CU of work)
constexpr int NT = BN / TN;               // 64 tiles per dim
constexpr int NBLK = NT * (NT + 1) / 2;   // 2080 triangular tile-pairs
constexpr float MARGIN = 0.2f;
constexpr uint32_t INF_U = 0x7f800000u;   // +inf bits; positive-float order == uint order

typedef __attribute__((ext_vector_type(8))) short short8;     // 8 bf16 = 4 VGPRs (MFMA A/B frag)
typedef __attribute__((ext_vector_type(4))) float float4v;    // MFMA C/D frag

// ---------------------------------------------------------------------------
// Kernel 1: per-row stats + bf16 cast of anchor + init of min arrays + counter.
// One wave per row (4 rows / 256-thread block). Lane l owns elems [8l, 8l+8).
// meta[row] = {||a||^2, d_ap(squared), d_ap^2, label-bits}  (one b128 load later)
// ---------------------------------------------------------------------------
__global__ __launch_bounds__(256) void prep_kernel(
    const float* __restrict__ anchor,
    const float* __restrict__ positive,
    const int* __restrict__ labels,
    uint16_t* __restrict__ Abf,        // [BN][DN] bf16 bits
    float4* __restrict__ meta,         // [BN]
    uint32_t* __restrict__ min_all,    // [BN] +inf-initialized (min over d2)
    uint32_t* __restrict__ min_larger, // [BN] +inf-initialized (min over d2)
    uint32_t* __restrict__ done_count) // single counter, zeroed here
{
    const int tid  = threadIdx.x;
    const int wave = tid >> 6;
    const int lane = tid & 63;
    const int row  = blockIdx.x * 4 + wave;

    if (blockIdx.x == 0 && tid == 0) *done_count = 0;

    const float4* arow = (const float4*)(anchor   + (size_t)row * DN);
    const float4* prow = (const float4*)(positive + (size_t)row * DN);

    float4 av0 = arow[lane * 2 + 0], av1 = arow[lane * 2 + 1];
    float4 pv0 = prow[lane * 2 + 0], pv1 = prow[lane * 2 + 1];

    float a[8] = {av0.x, av0.y, av0.z, av0.w, av1.x, av1.y, av1.z, av1.w};
    float p[8] = {pv0.x, pv0.y, pv0.z, pv0.w, pv1.x, pv1.y, pv1.z, pv1.w};

    float s = 0.f, d = 0.f;
    union { uint16_t u[8]; uint4 v; } pk;
    #pragma unroll
    for (int i = 0; i < 8; ++i) {
        s += a[i] * a[i];
        float dx = a[i] - p[i];
        d += dx * dx;
        uint32_t ub = __float_as_uint(a[i]);               // RNE f32 -> bf16
        pk.u[i] = (uint16_t)((ub + 0x7fffu + ((ub >> 16) & 1u)) >> 16);
    }

    ((uint4*)(Abf + (size_t)row * DN))[lane] = pk.v;       // 16B coalesced store

    #pragma unroll
    for (int off = 32; off; off >>= 1) {
        s += __shfl_xor(s, off);
        d += __shfl_xor(d, off);
    }
    if (lane == 0) {
        meta[row] = (float4){s, d, d * d, __uint_as_float((uint32_t)labels[row])};
        min_all[row]    = INF_U;
        min_larger[row] = INF_U;
    }
}

// ---------------------------------------------------------------------------
// Kernel 2: upper-triangular 64x64 tiles of S = A·A^T (bf16 MFMA 16x16x32).
// WHY 64x64 (R2 change): at 128x128 only 528 blocks exist -> 2 blocks/CU hard
// cap -> OccupancyPercent 14.7% and every structure is latency-bound (R1:
// no-LDS direct loads were 16-way address-divergent AND unhidden -> 72 us,
// MfmaUtil 4.4%). 64x64 gives 2080 blocks (~4-5 co-resident/CU at ~100 VGPR,
// 16-20 waves/CU) so the proven coalesced-staging skeleton gets its latency
// hidden by TLP. Staging: plain uint4 global loads (contiguous 128 B per 8
// lanes) -> ds_write_b128 with XOR-8 swizzle (0 conflicts measured); NO
// global_load_lds (serialized ~2.2k cyc/instr in this setting, earlier
// session). T14-lite: next K-step's 4 global loads issue BEFORE this step's
// ds_writes (compiler emits counted vmcnt(4)), so HBM/L2 latency hides under
// write+barrier+MFMA. Epilogue: squared-distance dual-side masked mins via
// uint atomicMin; meta float4 gives sqn/dap/dap^2/label in one b128 load.
// Last block (device counter) folds in the finalize: select, sqrt, hinge, mean.
// ---------------------------------------------------------------------------
__global__ __launch_bounds__(256, 4) void gram_kernel(
    const uint16_t* __restrict__ Abf,
    const float4* __restrict__ meta,
    uint32_t* __restrict__ min_all,
    uint32_t* __restrict__ min_larger,
    uint32_t* __restrict__ done_count,
    float* __restrict__ out)
{
    __shared__ uint16_t Abuf[TN * 64];   // 8 KB, row stride 64 elem = 128 B = 32 banks
    __shared__ uint16_t Bbuf[TN * 64];   // 8 KB

    // triangular decode: blockIdx.x -> (bi, bj) with bi <= bj
    int t = blockIdx.x, bi = 0, rem = NT;
    while (t >= rem) { t -= rem; ++bi; --rem; }
    const int bj = bi + t;
    const bool offdiag = (bi != bj);
    const int rowBase = bi * TN;
    const int colBase = bj * TN;

    const int tid  = threadIdx.x;
    const int wave = tid >> 6;
    const int lane = tid & 63;
    const int wi   = wave >> 1;       // wave row in 2x2 grid (32-row halves)
    const int wj   = wave & 1;        // wave col (32-col halves)
    const int quad = lane >> 4;
    const int l15  = lane & 15;

    // Staging map: per K-step each buffer = 64 rows x 8 chunks of 16 B = 512
    // chunks; thread handles chunks l = tid + i*256 (i=0,1): row sr = l>>3,
    // global chunk sc = l&7, LDS slot sp = sc ^ (sr&7)  (XOR swizzle).
    int sr[2], sc[2], sp[2];
    #pragma unroll
    for (int i = 0; i < 2; ++i) {
        int l = tid + i * 256;
        sr[i] = l >> 3; sc[i] = l & 7; sp[i] = sc[i] ^ (sr[i] & 7);
    }

    float4v acc[2][2];
    #pragma unroll
    for (int i = 0; i < 2; ++i)
        #pragma unroll
        for (int j = 0; j < 2; ++j)
            acc[i][j] = (float4v){0.f, 0.f, 0.f, 0.f};

    // prologue: loads for K-step 0
    uint4 stA[2], stB[2];
    #pragma unroll
    for (int i = 0; i < 2; ++i) {
        stA[i] = *(const uint4*)(Abf + (size_t)(rowBase + sr[i]) * DN + sc[i] * 8);
        stB[i] = *(const uint4*)(Abf + (size_t)(colBase + sr[i]) * DN + sc[i] * 8);
    }

    #pragma unroll
    for (int kt = 0; kt < DN / 64; ++kt) {           // 8 K-steps, fully unrolled
        __syncthreads();              // readers of previous step done
        // issue NEXT step's loads first -> overlap write+barrier+MFMA below
        uint4 nA[2], nB[2];
        if (kt < DN / 64 - 1) {
            const int k0 = (kt + 1) * 64;
            #pragma unroll
            for (int i = 0; i < 2; ++i) {
                nA[i] = *(const uint4*)(Abf + (size_t)(rowBase + sr[i]) * DN + k0 + sc[i] * 8);
                nB[i] = *(const uint4*)(Abf + (size_t)(colBase + sr[i]) * DN + k0 + sc[i] * 8);
            }
        }
        // write current step (compiler waits only the OLDER loads: vmcnt(4))
        #pragma unroll
        for (int i = 0; i < 2; ++i) {
            *(uint4*)(Abuf + sr[i] * 64 + sp[i] * 8) = stA[i];
            *(uint4*)(Bbuf + sr[i] * 64 + sp[i] * 8) = stB[i];
        }
        __syncthreads();              // LDS tiles visible

        #pragma unroll
        for (int kk = 0; kk < 2; ++kk) {
            short8 af[2], bfr[2];
            #pragma unroll
            for (int mi = 0; mi < 2; ++mi) {
                int r = wi * 32 + mi * 16 + l15;
                int p = (kk * 4 + quad) ^ (r & 7);
                af[mi] = *(const short8*)(Abuf + r * 64 + p * 8);
            }
            #pragma unroll
            for (int mj = 0; mj < 2; ++mj) {
                int r = wj * 32 + mj * 16 + l15;
                int p = (kk * 4 + quad) ^ (r & 7);
                bfr[mj] = *(const short8*)(Bbuf + r * 64 + p * 8);
            }
            #pragma unroll
            for (int mi = 0; mi < 2; ++mi)
                #pragma unroll
                for (int mj = 0; mj < 2; ++mj)
                    acc[mi][mj] = __builtin_amdgcn_mfma_f32_16x16x32_bf16(
                        af[mi], bfr[mj], acc[mi][mj], 0, 0, 0);
        }
        #pragma unroll
        for (int i = 0; i < 2; ++i) { stA[i] = nA[i]; stB[i] = nB[i]; }
    }

    // ---- epilogue: squared distances, dual-side masked mins ----
    const float INFF = __uint_as_float(INF_U);
    float4 mj_meta[2];
    #pragma unroll
    for (int mj = 0; mj < 2; ++mj)
        mj_meta[mj] = meta[colBase + wj * 32 + mj * 16 + l15];   // C/D col = lane&15

    float cAll[2], cLarger[2];
    #pragma unroll
    for (int mj = 0; mj < 2; ++mj) { cAll[mj] = INFF; cLarger[mj] = INFF; }

    #pragma unroll
    for (int mi = 0; mi < 2; ++mi) {
        #pragma unroll
        for (int r = 0; r < 4; ++r) {
            int row = rowBase + wi * 32 + mi * 16 + quad * 4 + r;  // C/D row = quad*4+reg
            float4 mim = meta[row];          // {sqn, dap, dap^2, label}
            uint32_t li = __float_as_uint(mim.w);
            float mAll = INFF, mLarger = INFF;
            #pragma unroll
            for (int mj = 0; mj < 2; ++mj) {
                float d2 = mim.x + mj_meta[mj].x - 2.0f * acc[mi][mj][r];
                d2 = d2 > 0.f ? d2 : 0.f;
                if (__float_as_uint(mj_meta[mj].w) != li) {
                    mAll = fminf(mAll, d2);
                    // reference: pd (euclidean) > d_ap (squared)  <=>  d2 > dap^2
                    if (d2 > mim.z) mLarger = fminf(mLarger, d2);
                    if (offdiag) {
                        cAll[mj] = fminf(cAll[mj], d2);
                        if (d2 > mj_meta[mj].z) cLarger[mj] = fminf(cLarger[mj], d2);
                    }
                }
            }
            // min across the 16 lanes of this quad (they share `row`, cover 32 cols)
            #pragma unroll
            for (int off = 1; off < 16; off <<= 1) {
                mAll    = fminf(mAll,    __shfl_xor(mAll, off));
                mLarger = fminf(mLarger, __shfl_xor(mLarger, off));
            }
            if (l15 == 0) {
                atomicMin(&min_all[row],    __float_as_uint(mAll));
                atomicMin(&min_larger[row], __float_as_uint(mLarger));
            }
        }
    }
    if (offdiag) {
        // col j = colBase + wj*32 + mj*16 + l15 is shared by the 4 quads
        #pragma unroll
        for (int mj = 0; mj < 2; ++mj) {
            float a0 = cAll[mj], l0 = cLarger[mj];
            a0 = fminf(a0, __shfl_xor(a0, 16)); l0 = fminf(l0, __shfl_xor(l0, 16));
            a0 = fminf(a0, __shfl_xor(a0, 32)); l0 = fminf(l0, __shfl_xor(l0, 32));
            if (quad == 0) {
                int col = colBase + wj * 32 + mj * 16 + l15;
                atomicMin(&min_all[col],    __float_as_uint(a0));
                atomicMin(&min_larger[col], __float_as_uint(l0));
            }
        }
    }

    // ---- last-block finalize: select, sqrt, hinge, mean ----
    __shared__ bool isLast;
    __syncthreads();                      // all this block's atomics issued
    if (tid == 0) {
        __threadfence();                  // make our mins visible device-wide
        isLast = (atomicAdd(done_count, 1u) == NBLK - 1);
    }
    __syncthreads();
    if (isLast) {
        __threadfence();                  // acquire: see all other blocks' mins
        float s = 0.f;
        for (int i = tid; i < BN; i += 256) {
            uint32_t mlu = __hip_atomic_load(&min_larger[i], __ATOMIC_RELAXED, __HIP_MEMORY_SCOPE_AGENT);
            uint32_t mau = __hip_atomic_load(&min_all[i],    __ATOMIC_RELAXED, __HIP_MEMORY_SCOPE_AGENT);
            float dan2 = (mlu != INF_U) ? __uint_as_float(mlu) : __uint_as_float(mau);
            float l = meta[i].y - sqrtf(dan2) + MARGIN;
            s += l > 0.f ? l : 0.f;
        }
        #pragma unroll
        for (int off = 32; off; off >>= 1) s += __shfl_xor(s, off);
        __shared__ float wsum[4];
        if ((tid & 63) == 0) wsum[tid >> 6] = s;
        __syncthreads();
        if (tid == 0) out[0] = (wsum[0] + wsum[1] + wsum[2] + wsum[3]) * (1.0f / BN);
    }
}

// ---------------------------------------------------------------------------
extern "C" void kernel_launch(void* const* d_in, const int* in_sizes, int n_in,
                              void* d_out, int out_size, void* d_ws, size_t ws_size,
                              hipStream_t stream) {
    const float* anchor   = (const float*)d_in[0];
    const float* positive = (const float*)d_in[1];
    const int*   labels   = (const int*)d_in[2];
    float* out = (float*)d_out;

    // Workspace layout (~4.4 MB)
    uint8_t* ws = (uint8_t*)d_ws;
    uint16_t* Abf        = (uint16_t*)ws;                          // 4 MB bf16 anchor
    float4*   meta       = (float4*)(ws + (size_t)BN * DN * 2);    // 64 KB
    uint32_t* min_all    = (uint32_t*)(meta + BN);                 // 16 KB
    uint32_t* min_larger = min_all + BN;                           // 16 KB
    uint32_t* done_count = min_larger + BN;                        // 4 B

    prep_kernel<<<BN / 4, 256, 0, stream>>>(anchor, positive, labels, Abf, meta,
                                            min_all, min_larger, done_count);
    gram_kernel<<<NBLK, 256, 0, stream>>>(Abf, meta, min_all, min_larger, done_count, out);
}

// Round 8
// 135.189 us; speedup vs baseline: 2.2870x; 2.2870x over previous
//
#include <hip/hip_runtime.h>
#include <hip/hip_bf16.h>
#include <cstdint>
#include <cstddef>

// Problem constants (fixed by the reference: anchor/positive [4096,512] f32, labels [4096] i32)
constexpr int BN = 4096;   // batch
constexpr int DN = 512;    // feature dim
constexpr int TN = 64;                    // tile edge (64x64 -> 2080 blocks ~ 8/CU of work)
constexpr int NT = BN / TN;               // 64 tiles per dim
constexpr int NBLK = NT * (NT + 1) / 2;   // 2080 triangular tile-pairs
constexpr float MARGIN = 0.2f;
constexpr uint32_t INF_U = 0x7f800000u;   // +inf bits; positive-float order == uint order

typedef __attribute__((ext_vector_type(8))) short short8;     // 8 bf16 = 4 VGPRs (MFMA A/B frag)
typedef __attribute__((ext_vector_type(4))) float float4v;    // MFMA C/D frag

// ---------------------------------------------------------------------------
// Kernel 1: per-row stats + bf16 cast of anchor + init of min arrays + counter.
// One wave per row (4 rows / 256-thread block). Lane l owns elems [8l, 8l+8).
// meta[row] = {||a||^2, d_ap(squared), d_ap^2, label-bits}  (one b128 load later)
// ---------------------------------------------------------------------------
__global__ __launch_bounds__(256) void prep_kernel(
    const float* __restrict__ anchor,
    const float* __restrict__ positive,
    const int* __restrict__ labels,
    uint16_t* __restrict__ Abf,        // [BN][DN] bf16 bits
    float4* __restrict__ meta,         // [BN]
    uint32_t* __restrict__ min_all,    // [BN] +inf-initialized (min over d2)
    uint32_t* __restrict__ min_larger, // [BN] +inf-initialized (min over d2)
    uint32_t* __restrict__ done_count) // single counter, zeroed here
{
    const int tid  = threadIdx.x;
    const int wave = tid >> 6;
    const int lane = tid & 63;
    const int row  = blockIdx.x * 4 + wave;

    if (blockIdx.x == 0 && tid == 0) *done_count = 0;

    const float4* arow = (const float4*)(anchor   + (size_t)row * DN);
    const float4* prow = (const float4*)(positive + (size_t)row * DN);

    float4 av0 = arow[lane * 2 + 0], av1 = arow[lane * 2 + 1];
    float4 pv0 = prow[lane * 2 + 0], pv1 = prow[lane * 2 + 1];

    float a[8] = {av0.x, av0.y, av0.z, av0.w, av1.x, av1.y, av1.z, av1.w};
    float p[8] = {pv0.x, pv0.y, pv0.z, pv0.w, pv1.x, pv1.y, pv1.z, pv1.w};

    float s = 0.f, d = 0.f;
    union { uint16_t u[8]; uint4 v; } pk;
    #pragma unroll
    for (int i = 0; i < 8; ++i) {
        s += a[i] * a[i];
        float dx = a[i] - p[i];
        d += dx * dx;
        uint32_t ub = __float_as_uint(a[i]);               // RNE f32 -> bf16
        pk.u[i] = (uint16_t)((ub + 0x7fffu + ((ub >> 16) & 1u)) >> 16);
    }

    ((uint4*)(Abf + (size_t)row * DN))[lane] = pk.v;       // 16B coalesced store

    #pragma unroll
    for (int off = 32; off; off >>= 1) {
        s += __shfl_xor(s, off);
        d += __shfl_xor(d, off);
    }
    if (lane == 0) {
        meta[row] = (float4){s, d, d * d, __uint_as_float((uint32_t)labels[row])};
        min_all[row]    = INF_U;
        min_larger[row] = INF_U;
    }
}

// ---------------------------------------------------------------------------
// Kernel 2: upper-triangular 64x64 tiles of S = A·A^T (bf16 MFMA 16x16x32).
// WHY 64x64: at 128x128 only 528 blocks exist -> 2 blocks/CU cap -> latency-
// bound (R1: MfmaUtil 4.4%, Occupancy 14.7%). 64x64 gives 2080 blocks; R4
// confirmed occupancy rises (48% even while spilling).
// WHY NO CROSS-BARRIER LIVENESS (R5 fix): R4 held next-step loads in
// registers across two barriers -> allocator spilled (VGPR 40, ~1 KB/thread
// scratch, 500 MB HBM writes/dispatch, 247 us). Same failure the original
// session hit. All 4 staging loads are now issued AND consumed within one
// inter-barrier phase (they pipeline against each other under counted vmcnt);
// cross-phase latency is hidden by multi-block TLP, not register prefetch.
// launch_bounds(256,6): VGPR cap ~85 -> no forced spill, ~6 blocks/CU.
// Staging: plain uint4 global loads (contiguous 128 B per 8 lanes) ->
// ds_write_b128, XOR-8 swizzle on LDS slot (0 conflicts measured). NO
// global_load_lds (per-wave DMA chain serialized, earlier session).
// Epilogue: squared-distance dual-side masked mins via uint atomicMin; meta
// float4 gives sqn/dap/dap^2/label in one b128 load. Last block (device
// counter) folds in the finalize: select, sqrt, hinge, mean.
// ---------------------------------------------------------------------------
__global__ __launch_bounds__(256, 6) void gram_kernel(
    const uint16_t* __restrict__ Abf,
    const float4* __restrict__ meta,
    uint32_t* __restrict__ min_all,
    uint32_t* __restrict__ min_larger,
    uint32_t* __restrict__ done_count,
    float* __restrict__ out)
{
    __shared__ uint16_t Abuf[TN * 64];   // 8 KB, row stride 64 elem = 128 B = 32 banks
    __shared__ uint16_t Bbuf[TN * 64];   // 8 KB

    // triangular decode: blockIdx.x -> (bi, bj) with bi <= bj
    int t = blockIdx.x, bi = 0, rem = NT;
    while (t >= rem) { t -= rem; ++bi; --rem; }
    const int bj = bi + t;
    const bool offdiag = (bi != bj);
    const int rowBase = bi * TN;
    const int colBase = bj * TN;

    const int tid  = threadIdx.x;
    const int wave = tid >> 6;
    const int lane = tid & 63;
    const int wi   = wave >> 1;       // wave row in 2x2 grid (32-row halves)
    const int wj   = wave & 1;        // wave col (32-col halves)
    const int quad = lane >> 4;
    const int l15  = lane & 15;

    // Staging map: per K-step each buffer = 64 rows x 8 chunks of 16 B = 512
    // chunks; thread handles chunks l = tid + i*256 (i=0,1): row sr = l>>3,
    // global chunk sc = l&7, LDS slot sp = sc ^ (sr&7)  (XOR swizzle).
    int sr[2], sc[2], sp[2];
    #pragma unroll
    for (int i = 0; i < 2; ++i) {
        int l = tid + i * 256;
        sr[i] = l >> 3; sc[i] = l & 7; sp[i] = sc[i] ^ (sr[i] & 7);
    }

    float4v acc[2][2];
    #pragma unroll
    for (int i = 0; i < 2; ++i)
        #pragma unroll
        for (int j = 0; j < 2; ++j)
            acc[i][j] = (float4v){0.f, 0.f, 0.f, 0.f};

    for (int kt = 0; kt < DN / 64; ++kt) {           // 8 K-steps
        const int k0 = kt * 64;
        __syncthreads();              // readers of previous step done
        {
            // 4 independent loads issue back-to-back (pipeline under vmcnt),
            // then 4 ds_writes; nothing stays live past the next barrier.
            uint4 sA[2], sB[2];
            #pragma unroll
            for (int i = 0; i < 2; ++i)
                sA[i] = *(const uint4*)(Abf + (size_t)(rowBase + sr[i]) * DN + k0 + sc[i] * 8);
            #pragma unroll
            for (int i = 0; i < 2; ++i)
                sB[i] = *(const uint4*)(Abf + (size_t)(colBase + sr[i]) * DN + k0 + sc[i] * 8);
            #pragma unroll
            for (int i = 0; i < 2; ++i)
                *(uint4*)(Abuf + sr[i] * 64 + sp[i] * 8) = sA[i];
            #pragma unroll
            for (int i = 0; i < 2; ++i)
                *(uint4*)(Bbuf + sr[i] * 64 + sp[i] * 8) = sB[i];
        }
        __syncthreads();              // LDS tiles visible

        #pragma unroll
        for (int kk = 0; kk < 2; ++kk) {
            short8 af[2], bfr[2];
            #pragma unroll
            for (int mi = 0; mi < 2; ++mi) {
                int r = wi * 32 + mi * 16 + l15;
                int p = (kk * 4 + quad) ^ (r & 7);
                af[mi] = *(const short8*)(Abuf + r * 64 + p * 8);
            }
            #pragma unroll
            for (int mj = 0; mj < 2; ++mj) {
                int r = wj * 32 + mj * 16 + l15;
                int p = (kk * 4 + quad) ^ (r & 7);
                bfr[mj] = *(const short8*)(Bbuf + r * 64 + p * 8);
            }
            #pragma unroll
            for (int mi = 0; mi < 2; ++mi)
                #pragma unroll
                for (int mj = 0; mj < 2; ++mj)
                    acc[mi][mj] = __builtin_amdgcn_mfma_f32_16x16x32_bf16(
                        af[mi], bfr[mj], acc[mi][mj], 0, 0, 0);
        }
    }

    // ---- epilogue: squared distances, dual-side masked mins ----
    const float INFF = __uint_as_float(INF_U);
    float4 mj_meta[2];
    #pragma unroll
    for (int mj = 0; mj < 2; ++mj)
        mj_meta[mj] = meta[colBase + wj * 32 + mj * 16 + l15];   // C/D col = lane&15

    float cAll[2], cLarger[2];
    #pragma unroll
    for (int mj = 0; mj < 2; ++mj) { cAll[mj] = INFF; cLarger[mj] = INFF; }

    #pragma unroll
    for (int mi = 0; mi < 2; ++mi) {
        #pragma unroll
        for (int r = 0; r < 4; ++r) {
            int row = rowBase + wi * 32 + mi * 16 + quad * 4 + r;  // C/D row = quad*4+reg
            float4 mim = meta[row];          // {sqn, dap, dap^2, label}
            uint32_t li = __float_as_uint(mim.w);
            float mAll = INFF, mLarger = INFF;
            #pragma unroll
            for (int mj = 0; mj < 2; ++mj) {
                float d2 = mim.x + mj_meta[mj].x - 2.0f * acc[mi][mj][r];
                d2 = d2 > 0.f ? d2 : 0.f;
                if (__float_as_uint(mj_meta[mj].w) != li) {
                    mAll = fminf(mAll, d2);
                    // reference: pd (euclidean) > d_ap (squared)  <=>  d2 > dap^2
                    if (d2 > mim.z) mLarger = fminf(mLarger, d2);
                    if (offdiag) {
                        cAll[mj] = fminf(cAll[mj], d2);
                        if (d2 > mj_meta[mj].z) cLarger[mj] = fminf(cLarger[mj], d2);
                    }
                }
            }
            // min across the 16 lanes of this quad (they share `row`, cover 32 cols)
            #pragma unroll
            for (int off = 1; off < 16; off <<= 1) {
                mAll    = fminf(mAll,    __shfl_xor(mAll, off));
                mLarger = fminf(mLarger, __shfl_xor(mLarger, off));
            }
            if (l15 == 0) {
                atomicMin(&min_all[row],    __float_as_uint(mAll));
                atomicMin(&min_larger[row], __float_as_uint(mLarger));
            }
        }
    }
    if (offdiag) {
        // col j = colBase + wj*32 + mj*16 + l15 is shared by the 4 quads
        #pragma unroll
        for (int mj = 0; mj < 2; ++mj) {
            float a0 = cAll[mj], l0 = cLarger[mj];
            a0 = fminf(a0, __shfl_xor(a0, 16)); l0 = fminf(l0, __shfl_xor(l0, 16));
            a0 = fminf(a0, __shfl_xor(a0, 32)); l0 = fminf(l0, __shfl_xor(l0, 32));
            if (quad == 0) {
                int col = colBase + wj * 32 + mj * 16 + l15;
                atomicMin(&min_all[col],    __float_as_uint(a0));
                atomicMin(&min_larger[col], __float_as_uint(l0));
            }
        }
    }

    // ---- last-block finalize: select, sqrt, hinge, mean ----
    __shared__ bool isLast;
    __syncthreads();                      // all this block's atomics issued
    if (tid == 0) {
        __threadfence();                  // make our mins visible device-wide
        isLast = (atomicAdd(done_count, 1u) == NBLK - 1);
    }
    __syncthreads();
    if (isLast) {
        __threadfence();                  // acquire: see all other blocks' mins
        float s = 0.f;
        for (int i = tid; i < BN; i += 256) {
            uint32_t mlu = __hip_atomic_load(&min_larger[i], __ATOMIC_RELAXED, __HIP_MEMORY_SCOPE_AGENT);
            uint32_t mau = __hip_atomic_load(&min_all[i],    __ATOMIC_RELAXED, __HIP_MEMORY_SCOPE_AGENT);
            float dan2 = (mlu != INF_U) ? __uint_as_float(mlu) : __uint_as_float(mau);
            float l = meta[i].y - sqrtf(dan2) + MARGIN;
            s += l > 0.f ? l : 0.f;
        }
        #pragma unroll
        for (int off = 32; off; off >>= 1) s += __shfl_xor(s, off);
        __shared__ float wsum[4];
        if ((tid & 63) == 0) wsum[tid >> 6] = s;
        __syncthreads();
        if (tid == 0) out[0] = (wsum[0] + wsum[1] + wsum[2] + wsum[3]) * (1.0f / BN);
    }
}

// ---------------------------------------------------------------------------
extern "C" void kernel_launch(void* const* d_in, const int* in_sizes, int n_in,
                              void* d_out, int out_size, void* d_ws, size_t ws_size,
                              hipStream_t stream) {
    const float* anchor   = (const float*)d_in[0];
    const float* positive = (const float*)d_in[1];
    const int*   labels   = (const int*)d_in[2];
    float* out = (float*)d_out;

    // Workspace layout (~4.4 MB)
    uint8_t* ws = (uint8_t*)d_ws;
    uint16_t* Abf        = (uint16_t*)ws;                          // 4 MB bf16 anchor
    float4*   meta       = (float4*)(ws + (size_t)BN * DN * 2);    // 64 KB
    uint32_t* min_all    = (uint32_t*)(meta + BN);                 // 16 KB
    uint32_t* min_larger = min_all + BN;                           // 16 KB
    uint32_t* done_count = min_larger + BN;                        // 4 B

    prep_kernel<<<BN / 4, 256, 0, stream>>>(anchor, positive, labels, Abf, meta,
                                            min_all, min_larger, done_count);
    gram_kernel<<<NBLK, 256, 0, stream>>>(Abf, meta, min_all, min_larger, done_count, out);
}

// Round 12
// 119.499 us; speedup vs baseline: 2.5872x; 1.1313x over previous
//
#include <hip/hip_runtime.h>
#include <hip/hip_bf16.h>
#include <cstdint>
#include <cstddef>

// Problem constants (fixed by the reference: anchor/positive [4096,512] f32, labels [4096] i32)
constexpr int BN = 4096;   // batch
constexpr int DN = 512;    // feature dim
constexpr int NT = BN / 128;              // 32 tiles per dim (128x128 tiles)
constexpr int NBLK = NT * (NT + 1) / 2;   // 528 triangular tile-pairs
constexpr float MARGIN = 0.2f;
constexpr uint32_t INF_U = 0x7f800000u;   // +inf bits; positive-float order == uint order

typedef __attribute__((ext_vector_type(8))) short short8;     // 8 bf16 = 4 VGPRs (MFMA A/B frag)
typedef __attribute__((ext_vector_type(4))) float float4v;    // MFMA C/D frag

// ---------------------------------------------------------------------------
// Kernel 1: per-row stats + bf16 cast of anchor + init of min arrays + counter.
// One wave per row (4 rows / 256-thread block). Lane l owns elems [8l, 8l+8).
// meta[row] = {||a||^2, d_ap(squared), d_ap^2, label-bits}  (one b128 load later)
// ---------------------------------------------------------------------------
__global__ __launch_bounds__(256) void prep_kernel(
    const float* __restrict__ anchor,
    const float* __restrict__ positive,
    const int* __restrict__ labels,
    uint16_t* __restrict__ Abf,        // [BN][DN] bf16 bits
    float4* __restrict__ meta,         // [BN]
    uint32_t* __restrict__ min_all,    // [BN] +inf-initialized (min over d2)
    uint32_t* __restrict__ min_larger, // [BN] +inf-initialized (min over d2)
    uint32_t* __restrict__ done_count) // single counter, zeroed here
{
    const int tid  = threadIdx.x;
    const int wave = tid >> 6;
    const int lane = tid & 63;
    const int row  = blockIdx.x * 4 + wave;

    if (blockIdx.x == 0 && tid == 0) *done_count = 0;

    const float4* arow = (const float4*)(anchor   + (size_t)row * DN);
    const float4* prow = (const float4*)(positive + (size_t)row * DN);

    float4 av0 = arow[lane * 2 + 0], av1 = arow[lane * 2 + 1];
    float4 pv0 = prow[lane * 2 + 0], pv1 = prow[lane * 2 + 1];

    float a[8] = {av0.x, av0.y, av0.z, av0.w, av1.x, av1.y, av1.z, av1.w};
    float p[8] = {pv0.x, pv0.y, pv0.z, pv0.w, pv1.x, pv1.y, pv1.z, pv1.w};

    float s = 0.f, d = 0.f;
    union { uint16_t u[8]; uint4 v; } pk;
    #pragma unroll
    for (int i = 0; i < 8; ++i) {
        s += a[i] * a[i];
        float dx = a[i] - p[i];
        d += dx * dx;
        uint32_t ub = __float_as_uint(a[i]);               // RNE f32 -> bf16
        pk.u[i] = (uint16_t)((ub + 0x7fffu + ((ub >> 16) & 1u)) >> 16);
    }

    ((uint4*)(Abf + (size_t)row * DN))[lane] = pk.v;       // 16B coalesced store

    #pragma unroll
    for (int off = 32; off; off >>= 1) {
        s += __shfl_xor(s, off);
        d += __shfl_xor(d, off);
    }
    if (lane == 0) {
        meta[row] = (float4){s, d, d * d, __uint_as_float((uint32_t)labels[row])};
        min_all[row]    = INF_U;
        min_larger[row] = INF_U;
    }
}

// ---------------------------------------------------------------------------
// Kernel 2: upper-triangular 128x128 tiles of S = A·A^T (bf16 MFMA 16x16x32).
// WHY 128x128 (back from 64x64): R8 proved occupancy is NOT the lever —
// 64x64 tiles tripled occupancy (44.5%) yet stayed at 72 us / 4.5% MfmaUtil,
// because each block's K-step is a load->barrier->tiny-compute->barrier
// latency chain and all waves stall together. 128x128 has 4x the MFMA work
// per exposed step (R0 baseline with it was <43 us).
// WHY BK=128 / 4 phases (R9 change vs R0's BK=64 / 8 steps): halves the
// barrier count (8 total) and quadruples per-phase MLP — each thread issues
// 16 independent uint4 loads (A:8 + B:8) back-to-back before one drain, so
// the L2/L3 latency (Abf=4MB thrashes the 4MiB/XCD L2) is paid ~4 times
// per block, not 8, and is better pipelined. LDS 2x32KB = 64KB -> 2
// blocks/CU overlap each other's load phases.
// Swizzle for 256B row stride: write slot sp = sc ^ (sr&15); read slot
// p = (kk*4+quad) ^ (r&15) -> 16 lanes land on 8 bank-groups 2-way (free).
// K-loop NOT unrolled: no cross-barrier register liveness (R4 spill lesson).
// Epilogue: verbatim from the verified 106us baseline (4x4 acc, dual-side
// masked mins via uint atomicMin, meta b128, last-block finalize).
// ---------------------------------------------------------------------------
__global__ __launch_bounds__(256, 2) void gram_kernel(
    const uint16_t* __restrict__ Abf,
    const float4* __restrict__ meta,
    uint32_t* __restrict__ min_all,
    uint32_t* __restrict__ min_larger,
    uint32_t* __restrict__ done_count,
    float* __restrict__ out)
{
    __shared__ uint16_t Abuf[128 * 128];   // 32 KB, row stride 128 elem = 256 B
    __shared__ uint16_t Bbuf[128 * 128];   // 32 KB

    // triangular decode: blockIdx.x -> (bi, bj) with bi <= bj
    int t = blockIdx.x, bi = 0, rem = NT;
    while (t >= rem) { t -= rem; ++bi; --rem; }
    const int bj = bi + t;
    const bool offdiag = (bi != bj);
    const int rowBase = bi * 128;
    const int colBase = bj * 128;

    const int tid  = threadIdx.x;
    const int wave = tid >> 6;
    const int lane = tid & 63;
    const int wi   = wave >> 1;       // wave row in 2x2 grid (64-row halves)
    const int wj   = wave & 1;        // wave col (64-col halves)
    const int quad = lane >> 4;
    const int l15  = lane & 15;

    // Staging map: per phase each buffer = 128 rows x 16 chunks of 16 B =
    // 2048 chunks; thread handles chunks l = tid + i*256 (i=0..7):
    // row sr = l>>4, chunk sc = l&15, LDS slot sp = sc ^ (sr&15).
    int sr[8], sc[8], sp[8];
    #pragma unroll
    for (int i = 0; i < 8; ++i) {
        int l = tid + i * 256;
        sr[i] = l >> 4; sc[i] = l & 15; sp[i] = sc[i] ^ (sr[i] & 15);
    }

    float4v acc[4][4];
    #pragma unroll
    for (int i = 0; i < 4; ++i)
        #pragma unroll
        for (int j = 0; j < 4; ++j)
            acc[i][j] = (float4v){0.f, 0.f, 0.f, 0.f};

    for (int kt = 0; kt < DN / 128; ++kt) {          // 4 phases (NOT unrolled)
        const int k0 = kt * 128;
        __syncthreads();              // readers of previous phase done
        {
            // 16 independent loads issue back-to-back (deep MLP, one drain),
            // then 16 ds_writes; nothing lives past the next barrier.
            uint4 sA[8], sB[8];
            #pragma unroll
            for (int i = 0; i < 8; ++i)
                sA[i] = *(const uint4*)(Abf + (size_t)(rowBase + sr[i]) * DN + k0 + sc[i] * 8);
            #pragma unroll
            for (int i = 0; i < 8; ++i)
                sB[i] = *(const uint4*)(Abf + (size_t)(colBase + sr[i]) * DN + k0 + sc[i] * 8);
            #pragma unroll
            for (int i = 0; i < 8; ++i)
                *(uint4*)(Abuf + sr[i] * 128 + sp[i] * 8) = sA[i];
            #pragma unroll
            for (int i = 0; i < 8; ++i)
                *(uint4*)(Bbuf + sr[i] * 128 + sp[i] * 8) = sB[i];
        }
        __syncthreads();              // LDS tiles visible

        #pragma unroll
        for (int kk = 0; kk < 4; ++kk) {             // 4 x K=32 sub-steps
            short8 af[4], bfr[4];
            #pragma unroll
            for (int mi = 0; mi < 4; ++mi) {
                int r = wi * 64 + mi * 16 + l15;
                int p = (kk * 4 + quad) ^ (r & 15);
                af[mi] = *(const short8*)(Abuf + r * 128 + p * 8);
            }
            #pragma unroll
            for (int mj = 0; mj < 4; ++mj) {
                int r = wj * 64 + mj * 16 + l15;
                int p = (kk * 4 + quad) ^ (r & 15);
                bfr[mj] = *(const short8*)(Bbuf + r * 128 + p * 8);
            }
            #pragma unroll
            for (int mi = 0; mi < 4; ++mi)
                #pragma unroll
                for (int mj = 0; mj < 4; ++mj)
                    acc[mi][mj] = __builtin_amdgcn_mfma_f32_16x16x32_bf16(
                        af[mi], bfr[mj], acc[mi][mj], 0, 0, 0);
        }
    }

    // ---- epilogue: squared distances, dual-side masked mins ----
    const float INFF = __uint_as_float(INF_U);
    float4 mj_meta[4];
    #pragma unroll
    for (int mj = 0; mj < 4; ++mj)
        mj_meta[mj] = meta[colBase + wj * 64 + mj * 16 + l15];   // C/D col = lane&15

    float cAll[4], cLarger[4];
    #pragma unroll
    for (int mj = 0; mj < 4; ++mj) { cAll[mj] = INFF; cLarger[mj] = INFF; }

    #pragma unroll
    for (int mi = 0; mi < 4; ++mi) {
        #pragma unroll
        for (int r = 0; r < 4; ++r) {
            int row = rowBase + wi * 64 + mi * 16 + quad * 4 + r;  // C/D row = quad*4+reg
            float4 mim = meta[row];          // {sqn, dap, dap^2, label}
            uint32_t li = __float_as_uint(mim.w);
            float mAll = INFF, mLarger = INFF;
            #pragma unroll
            for (int mj = 0; mj < 4; ++mj) {
                float d2 = mim.x + mj_meta[mj].x - 2.0f * acc[mi][mj][r];
                d2 = d2 > 0.f ? d2 : 0.f;
                if (__float_as_uint(mj_meta[mj].w) != li) {
                    mAll = fminf(mAll, d2);
                    // reference: pd (euclidean) > d_ap (squared)  <=>  d2 > dap^2
                    if (d2 > mim.z) mLarger = fminf(mLarger, d2);
                    if (offdiag) {
                        cAll[mj] = fminf(cAll[mj], d2);
                        if (d2 > mj_meta[mj].z) cLarger[mj] = fminf(cLarger[mj], d2);
                    }
                }
            }
            // min across the 16 lanes of this quad (they share `row`, cover 64 cols)
            #pragma unroll
            for (int off = 1; off < 16; off <<= 1) {
                mAll    = fminf(mAll,    __shfl_xor(mAll, off));
                mLarger = fminf(mLarger, __shfl_xor(mLarger, off));
            }
            if (l15 == 0) {
                atomicMin(&min_all[row],    __float_as_uint(mAll));
                atomicMin(&min_larger[row], __float_as_uint(mLarger));
            }
        }
    }
    if (offdiag) {
        // col j = colBase + wj*64 + mj*16 + l15 is shared by the 4 quads
        #pragma unroll
        for (int mj = 0; mj < 4; ++mj) {
            float a0 = cAll[mj], l0 = cLarger[mj];
            a0 = fminf(a0, __shfl_xor(a0, 16)); l0 = fminf(l0, __shfl_xor(l0, 16));
            a0 = fminf(a0, __shfl_xor(a0, 32)); l0 = fminf(l0, __shfl_xor(l0, 32));
            if (quad == 0) {
                int col = colBase + wj * 64 + mj * 16 + l15;
                atomicMin(&min_all[col],    __float_as_uint(a0));
                atomicMin(&min_larger[col], __float_as_uint(l0));
            }
        }
    }

    // ---- last-block finalize: select, sqrt, hinge, mean ----
    __shared__ bool isLast;
    __syncthreads();                      // all this block's atomics issued
    if (tid == 0) {
        __threadfence();                  // make our mins visible device-wide
        isLast = (atomicAdd(done_count, 1u) == NBLK - 1);
    }
    __syncthreads();
    if (isLast) {
        __threadfence();                  // acquire: see all other blocks' mins
        float s = 0.f;
        for (int i = tid; i < BN; i += 256) {
            uint32_t mlu = __hip_atomic_load(&min_larger[i], __ATOMIC_RELAXED, __HIP_MEMORY_SCOPE_AGENT);
            uint32_t mau = __hip_atomic_load(&min_all[i],    __ATOMIC_RELAXED, __HIP_MEMORY_SCOPE_AGENT);
            float dan2 = (mlu != INF_U) ? __uint_as_float(mlu) : __uint_as_float(mau);
            float l = meta[i].y - sqrtf(dan2) + MARGIN;
            s += l > 0.f ? l : 0.f;
        }
        #pragma unroll
        for (int off = 32; off; off >>= 1) s += __shfl_xor(s, off);
        __shared__ float wsum[4];
        if ((tid & 63) == 0) wsum[tid >> 6] = s;
        __syncthreads();
        if (tid == 0) out[0] = (wsum[0] + wsum[1] + wsum[2] + wsum[3]) * (1.0f / BN);
    }
}

// ---------------------------------------------------------------------------
extern "C" void kernel_launch(void* const* d_in, const int* in_sizes, int n_in,
                              void* d_out, int out_size, void* d_ws, size_t ws_size,
                              hipStream_t stream) {
    const float* anchor   = (const float*)d_in[0];
    const float* positive = (const float*)d_in[1];
    const int*   labels   = (const int*)d_in[2];
    float* out = (float*)d_out;

    // Workspace layout (~4.4 MB)
    uint8_t* ws = (uint8_t*)d_ws;
    uint16_t* Abf        = (uint16_t*)ws;                          // 4 MB bf16 anchor
    float4*   meta       = (float4*)(ws + (size_t)BN * DN * 2);    // 64 KB
    uint32_t* min_all    = (uint32_t*)(meta + BN);                 // 16 KB
    uint32_t* min_larger = min_all + BN;                           // 16 KB
    uint32_t* done_count = min_larger + BN;                        // 4 B

    prep_kernel<<<BN / 4, 256, 0, stream>>>(anchor, positive, labels, Abf, meta,
                                            min_all, min_larger, done_count);
    gram_kernel<<<NBLK, 256, 0, stream>>>(Abf, meta, min_all, min_larger, done_count, out);
}

// Round 14
// 110.348 us; speedup vs baseline: 2.8018x; 1.0829x over previous
//
#include <hip/hip_runtime.h>
#include <hip/hip_bf16.h>
#include <cstdint>
#include <cstddef>

// Problem constants (fixed by the reference: anchor/positive [4096,512] f32, labels [4096] i32)
constexpr int BN = 4096;   // batch
constexpr int DN = 512;    // feature dim
constexpr int NT = BN / 128;              // 32 tiles per dim (128x128 tiles)
constexpr int NBLK = NT * (NT + 1) / 2;   // 528 triangular tile-pairs
constexpr float MARGIN = 0.2f;
constexpr uint32_t INF_U = 0x7f800000u;   // +inf bits; positive-float order == uint order

typedef __attribute__((ext_vector_type(8))) short short8;     // 8 bf16 = 4 VGPRs (MFMA A/B frag)
typedef __attribute__((ext_vector_type(4))) float float4v;    // MFMA C/D frag

// ---------------------------------------------------------------------------
// Kernel 1: per-row stats + bf16 cast of anchor + counter zero.
// One wave per row (4 rows / 256-thread block). Lane l owns elems [8l, 8l+8).
// meta[row] = {||a||^2, d_ap(squared), d_ap^2, label-bits}
// ---------------------------------------------------------------------------
__global__ __launch_bounds__(256) void prep_kernel(
    const float* __restrict__ anchor,
    const float* __restrict__ positive,
    const int* __restrict__ labels,
    uint16_t* __restrict__ Abf,        // [BN][DN] bf16 bits
    float4* __restrict__ meta,         // [BN]
    uint32_t* __restrict__ done_count) // single counter (finalize), zeroed here
{
    const int tid  = threadIdx.x;
    const int wave = tid >> 6;
    const int lane = tid & 63;
    const int row  = blockIdx.x * 4 + wave;

    if (blockIdx.x == 0 && tid == 0) *done_count = 0;

    const float4* arow = (const float4*)(anchor   + (size_t)row * DN);
    const float4* prow = (const float4*)(positive + (size_t)row * DN);

    float4 av0 = arow[lane * 2 + 0], av1 = arow[lane * 2 + 1];
    float4 pv0 = prow[lane * 2 + 0], pv1 = prow[lane * 2 + 1];

    float a[8] = {av0.x, av0.y, av0.z, av0.w, av1.x, av1.y, av1.z, av1.w};
    float p[8] = {pv0.x, pv0.y, pv0.z, pv0.w, pv1.x, pv1.y, pv1.z, pv1.w};

    float s = 0.f, d = 0.f;
    union { uint16_t u[8]; uint4 v; } pk;
    #pragma unroll
    for (int i = 0; i < 8; ++i) {
        s += a[i] * a[i];
        float dx = a[i] - p[i];
        d += dx * dx;
        uint32_t ub = __float_as_uint(a[i]);               // RNE f32 -> bf16
        pk.u[i] = (uint16_t)((ub + 0x7fffu + ((ub >> 16) & 1u)) >> 16);
    }

    ((uint4*)(Abf + (size_t)row * DN))[lane] = pk.v;       // 16B coalesced store

    #pragma unroll
    for (int off = 32; off; off >>= 1) {
        s += __shfl_xor(s, off);
        d += __shfl_xor(d, off);
    }
    if (lane == 0)
        meta[row] = (float4){s, d, d * d, __uint_as_float((uint32_t)labels[row])};
}

// ---------------------------------------------------------------------------
// Kernel 2: upper-triangular 128x128 tiles of S = A·A^T (bf16 MFMA 16x16x32).
// R13 = ABLATION ROUND. Evidence: R1 (no LDS, 0 barriers), R8 (64^2, 16
// barriers, 44% occ) and R12 (128^2, 8 barriers, deep MLP) ALL land at
// 72-75 us with MfmaUtil ~4.4% and every pipe <10% busy. The K-loop is
// exonerated — the invariant across all versions is the EPILOGUE: ~0.5-1M
// device-scope atomicMin (cross-XCD -> executed at the L3 coherence point,
// ~600-900cyc, per-line serialized) + a per-block __threadfence (cross-XCD
// release: vmcnt(0) drain + L2 writeback). This round REMOVES that path
// entirely, keeping the K-loop byte-identical to R12 so the delta is
// attributable: each (row,slot) partial min has exactly ONE writer ->
// plain stores to partial[row][32]; no atomics, no fence, no done-counter
// in gram. finalize_kernel (16 blocks) reduces the 32 slots/row.
// Slot coverage proof: row in tile t gets slot s>=t from row-side of block
// (t,s) (incl. diagonal s==t) and slot s<t from col-side of block (s,t);
// each of the 32 slots written exactly once.
// ---------------------------------------------------------------------------
__global__ __launch_bounds__(256, 2) void gram_kernel(
    const uint16_t* __restrict__ Abf,
    const float4* __restrict__ meta,
    uint32_t* __restrict__ partial_all,     // [BN][NT] +inf-or-min d2 bits
    uint32_t* __restrict__ partial_larger)  // [BN][NT]
{
    __shared__ uint16_t Abuf[128 * 128];   // 32 KB, row stride 128 elem = 256 B
    __shared__ uint16_t Bbuf[128 * 128];   // 32 KB

    // triangular decode: blockIdx.x -> (bi, bj) with bi <= bj
    int t = blockIdx.x, bi = 0, rem = NT;
    while (t >= rem) { t -= rem; ++bi; --rem; }
    const int bj = bi + t;
    const bool offdiag = (bi != bj);
    const int rowBase = bi * 128;
    const int colBase = bj * 128;

    const int tid  = threadIdx.x;
    const int wave = tid >> 6;
    const int lane = tid & 63;
    const int wi   = wave >> 1;       // wave row in 2x2 grid (64-row halves)
    const int wj   = wave & 1;        // wave col (64-col halves)
    const int quad = lane >> 4;
    const int l15  = lane & 15;

    // Staging map: per phase each buffer = 128 rows x 16 chunks of 16 B =
    // 2048 chunks; thread handles chunks l = tid + i*256 (i=0..7):
    // row sr = l>>4, chunk sc = l&15, LDS slot sp = sc ^ (sr&15).
    int sr[8], sc[8], sp[8];
    #pragma unroll
    for (int i = 0; i < 8; ++i) {
        int l = tid + i * 256;
        sr[i] = l >> 4; sc[i] = l & 15; sp[i] = sc[i] ^ (sr[i] & 15);
    }

    float4v acc[4][4];
    #pragma unroll
    for (int i = 0; i < 4; ++i)
        #pragma unroll
        for (int j = 0; j < 4; ++j)
            acc[i][j] = (float4v){0.f, 0.f, 0.f, 0.f};

    for (int kt = 0; kt < DN / 128; ++kt) {          // 4 phases (NOT unrolled)
        const int k0 = kt * 128;
        __syncthreads();              // readers of previous phase done
        {
            // 16 independent loads issue back-to-back (deep MLP, one drain),
            // then 16 ds_writes; nothing lives past the next barrier.
            uint4 sA[8], sB[8];
            #pragma unroll
            for (int i = 0; i < 8; ++i)
                sA[i] = *(const uint4*)(Abf + (size_t)(rowBase + sr[i]) * DN + k0 + sc[i] * 8);
            #pragma unroll
            for (int i = 0; i < 8; ++i)
                sB[i] = *(const uint4*)(Abf + (size_t)(colBase + sr[i]) * DN + k0 + sc[i] * 8);
            #pragma unroll
            for (int i = 0; i < 8; ++i)
                *(uint4*)(Abuf + sr[i] * 128 + sp[i] * 8) = sA[i];
            #pragma unroll
            for (int i = 0; i < 8; ++i)
                *(uint4*)(Bbuf + sr[i] * 128 + sp[i] * 8) = sB[i];
        }
        __syncthreads();              // LDS tiles visible

        #pragma unroll
        for (int kk = 0; kk < 4; ++kk) {             // 4 x K=32 sub-steps
            short8 af[4], bfr[4];
            #pragma unroll
            for (int mi = 0; mi < 4; ++mi) {
                int r = wi * 64 + mi * 16 + l15;
                int p = (kk * 4 + quad) ^ (r & 15);
                af[mi] = *(const short8*)(Abuf + r * 128 + p * 8);
            }
            #pragma unroll
            for (int mj = 0; mj < 4; ++mj) {
                int r = wj * 64 + mj * 16 + l15;
                int p = (kk * 4 + quad) ^ (r & 15);
                bfr[mj] = *(const short8*)(Bbuf + r * 128 + p * 8);
            }
            #pragma unroll
            for (int mi = 0; mi < 4; ++mi)
                #pragma unroll
                for (int mj = 0; mj < 4; ++mj)
                    acc[mi][mj] = __builtin_amdgcn_mfma_f32_16x16x32_bf16(
                        af[mi], bfr[mj], acc[mi][mj], 0, 0, 0);
        }
    }

    // ---- epilogue: squared distances, dual-side masked mins, PLAIN STORES ----
    const float INFF = __uint_as_float(INF_U);
    float4 mj_meta[4];
    #pragma unroll
    for (int mj = 0; mj < 4; ++mj)
        mj_meta[mj] = meta[colBase + wj * 64 + mj * 16 + l15];   // C/D col = lane&15

    float cAll[4], cLarger[4];
    #pragma unroll
    for (int mj = 0; mj < 4; ++mj) { cAll[mj] = INFF; cLarger[mj] = INFF; }

    #pragma unroll
    for (int mi = 0; mi < 4; ++mi) {
        #pragma unroll
        for (int r = 0; r < 4; ++r) {
            int row = rowBase + wi * 64 + mi * 16 + quad * 4 + r;  // C/D row = quad*4+reg
            float4 mim = meta[row];          // {sqn, dap, dap^2, label}
            uint32_t li = __float_as_uint(mim.w);
            float mAll = INFF, mLarger = INFF;
            #pragma unroll
            for (int mj = 0; mj < 4; ++mj) {
                float d2 = mim.x + mj_meta[mj].x - 2.0f * acc[mi][mj][r];
                d2 = d2 > 0.f ? d2 : 0.f;
                if (__float_as_uint(mj_meta[mj].w) != li) {
                    mAll = fminf(mAll, d2);
                    // reference: pd (euclidean) > d_ap (squared)  <=>  d2 > dap^2
                    if (d2 > mim.z) mLarger = fminf(mLarger, d2);
                    if (offdiag) {
                        cAll[mj] = fminf(cAll[mj], d2);
                        if (d2 > mj_meta[mj].z) cLarger[mj] = fminf(cLarger[mj], d2);
                    }
                }
            }
            // min across the 16 lanes of this quad (they share `row`, cover 64 cols)
            #pragma unroll
            for (int off = 1; off < 16; off <<= 1) {
                mAll    = fminf(mAll,    __shfl_xor(mAll, off));
                mLarger = fminf(mLarger, __shfl_xor(mLarger, off));
            }
            if (l15 == 0) {
                partial_all   [(size_t)row * NT + bj] = __float_as_uint(mAll);
                partial_larger[(size_t)row * NT + bj] = __float_as_uint(mLarger);
            }
        }
    }
    if (offdiag) {
        // col j = colBase + wj*64 + mj*16 + l15 is shared by the 4 quads
        #pragma unroll
        for (int mj = 0; mj < 4; ++mj) {
            float a0 = cAll[mj], l0 = cLarger[mj];
            a0 = fminf(a0, __shfl_xor(a0, 16)); l0 = fminf(l0, __shfl_xor(l0, 16));
            a0 = fminf(a0, __shfl_xor(a0, 32)); l0 = fminf(l0, __shfl_xor(l0, 32));
            if (quad == 0) {
                int col = colBase + wj * 64 + mj * 16 + l15;
                partial_all   [(size_t)col * NT + bi] = __float_as_uint(a0);
                partial_larger[(size_t)col * NT + bi] = __float_as_uint(l0);
            }
        }
    }
    // no fence, no counter — block just ends
}

// ---------------------------------------------------------------------------
// Kernel 3: per-row reduce of the 32 slots, select/sqrt/hinge, deterministic
// 16-way sum. 16 blocks x 256 threads, one row per thread.
// ---------------------------------------------------------------------------
__global__ __launch_bounds__(256) void finalize_kernel(
    const float4* __restrict__ meta,
    const uint32_t* __restrict__ partial_all,
    const uint32_t* __restrict__ partial_larger,
    float* __restrict__ psum,          // [16]
    uint32_t* __restrict__ done_count,
    float* __restrict__ out)
{
    const int tid = threadIdx.x;
    const int row = blockIdx.x * 256 + tid;
    const float INFF = __uint_as_float(INF_U);

    float mAll = INFF, mLarger = INFF;
    const uint4* pa = (const uint4*)(partial_all    + (size_t)row * NT);
    const uint4* pl = (const uint4*)(partial_larger + (size_t)row * NT);
    #pragma unroll
    for (int i = 0; i < 8; ++i) {
        uint4 a = pa[i], l = pl[i];
        mAll = fminf(mAll, fminf(fminf(__uint_as_float(a.x), __uint_as_float(a.y)),
                                 fminf(__uint_as_float(a.z), __uint_as_float(a.w))));
        mLarger = fminf(mLarger, fminf(fminf(__uint_as_float(l.x), __uint_as_float(l.y)),
                                       fminf(__uint_as_float(l.z), __uint_as_float(l.w))));
    }
    float dan2 = (__float_as_uint(mLarger) != INF_U) ? mLarger : mAll;
    float lv = meta[row].y - sqrtf(dan2) + MARGIN;
    float s = lv > 0.f ? lv : 0.f;

    #pragma unroll
    for (int off = 32; off; off >>= 1) s += __shfl_xor(s, off);
    __shared__ float wsum[4];
    if ((tid & 63) == 0) wsum[tid >> 6] = s;
    __syncthreads();

    __shared__ bool isLast;
    if (tid == 0) {
        psum[blockIdx.x] = wsum[0] + wsum[1] + wsum[2] + wsum[3];
        __threadfence();
        isLast = (atomicAdd(done_count, 1u) == 16 - 1);
    }
    __syncthreads();
    if (isLast && tid == 0) {
        __threadfence();
        float tot = 0.f;
        for (int b = 0; b < 16; ++b)
            tot += __hip_atomic_load(&psum[b], __ATOMIC_RELAXED, __HIP_MEMORY_SCOPE_AGENT);
        out[0] = tot * (1.0f / BN);
    }
}

// ---------------------------------------------------------------------------
extern "C" void kernel_launch(void* const* d_in, const int* in_sizes, int n_in,
                              void* d_out, int out_size, void* d_ws, size_t ws_size,
                              hipStream_t stream) {
    const float* anchor   = (const float*)d_in[0];
    const float* positive = (const float*)d_in[1];
    const int*   labels   = (const int*)d_in[2];
    float* out = (float*)d_out;

    // Workspace layout (~5.1 MB)
    uint8_t* ws = (uint8_t*)d_ws;
    uint16_t* Abf            = (uint16_t*)ws;                        // 4 MB bf16 anchor
    float4*   meta           = (float4*)(ws + (size_t)BN * DN * 2);  // 64 KB
    uint32_t* partial_all    = (uint32_t*)(meta + BN);               // 512 KB
    uint32_t* partial_larger = partial_all + (size_t)BN * NT;        // 512 KB
    float*    psum           = (float*)(partial_larger + (size_t)BN * NT); // 64 B
    uint32_t* done_count     = (uint32_t*)(psum + 16);               // 4 B

    prep_kernel<<<BN / 4, 256, 0, stream>>>(anchor, positive, labels, Abf, meta, done_count);
    gram_kernel<<<NBLK, 256, 0, stream>>>(Abf, meta, partial_all, partial_larger);
    finalize_kernel<<<16, 256, 0, stream>>>(meta, partial_all, partial_larger,
                                            psum, done_count, out);
}

// Round 15
// 106.769 us; speedup vs baseline: 2.8957x; 1.0335x over previous
//
#include <hip/hip_runtime.h>
#include <hip/hip_bf16.h>
#include <cstdint>
#include <cstddef>

// Problem constants (fixed by the reference: anchor/positive [4096,512] f32, labels [4096] i32)
constexpr int BN = 4096;   // batch
constexpr int DN = 512;    // feature dim
constexpr int NT = BN / 128;              // 32 tiles per dim (128x128 tiles)
constexpr int NBLK = NT * (NT + 1) / 2;   // 528 triangular tile-pairs
constexpr float MARGIN = 0.2f;
constexpr uint32_t INF_U = 0x7f800000u;   // +inf bits; positive-float order == uint order

typedef __attribute__((ext_vector_type(8))) short short8;     // 8 bf16 = 4 VGPRs (MFMA A/B frag)
typedef __attribute__((ext_vector_type(4))) float float4v;    // MFMA C/D frag

// ---------------------------------------------------------------------------
// Kernel 1: per-row stats + bf16 cast of anchor + counter zero.
// One wave per row (4 rows / 256-thread block). Lane l owns elems [8l, 8l+8).
// meta[row] = {||a||^2, d_ap(squared), d_ap^2, label-bits}
// ---------------------------------------------------------------------------
__global__ __launch_bounds__(256) void prep_kernel(
    const float* __restrict__ anchor,
    const float* __restrict__ positive,
    const int* __restrict__ labels,
    uint16_t* __restrict__ Abf,        // [BN][DN] bf16 bits
    float4* __restrict__ meta,         // [BN]
    uint32_t* __restrict__ done_count) // single counter (finalize), zeroed here
{
    const int tid  = threadIdx.x;
    const int wave = tid >> 6;
    const int lane = tid & 63;
    const int row  = blockIdx.x * 4 + wave;

    if (blockIdx.x == 0 && tid == 0) *done_count = 0;

    const float4* arow = (const float4*)(anchor   + (size_t)row * DN);
    const float4* prow = (const float4*)(positive + (size_t)row * DN);

    float4 av0 = arow[lane * 2 + 0], av1 = arow[lane * 2 + 1];
    float4 pv0 = prow[lane * 2 + 0], pv1 = prow[lane * 2 + 1];

    float a[8] = {av0.x, av0.y, av0.z, av0.w, av1.x, av1.y, av1.z, av1.w};
    float p[8] = {pv0.x, pv0.y, pv0.z, pv0.w, pv1.x, pv1.y, pv1.z, pv1.w};

    float s = 0.f, d = 0.f;
    union { uint16_t u[8]; uint4 v; } pk;
    #pragma unroll
    for (int i = 0; i < 8; ++i) {
        s += a[i] * a[i];
        float dx = a[i] - p[i];
        d += dx * dx;
        uint32_t ub = __float_as_uint(a[i]);               // RNE f32 -> bf16
        pk.u[i] = (uint16_t)((ub + 0x7fffu + ((ub >> 16) & 1u)) >> 16);
    }

    ((uint4*)(Abf + (size_t)row * DN))[lane] = pk.v;       // 16B coalesced store

    #pragma unroll
    for (int off = 32; off; off >>= 1) {
        s += __shfl_xor(s, off);
        d += __shfl_xor(d, off);
    }
    if (lane == 0)
        meta[row] = (float4){s, d, d * d, __uint_as_float((uint32_t)labels[row])};
}

// ---------------------------------------------------------------------------
// Kernel 2: upper-triangular 128x128 tiles of S = A·A^T (bf16 MFMA 16x16x32).
// R15 = combine the two best-measured components:
//  - K-LOOP from the R0 baseline (BK=64, 8 phases, XOR-8 swizzle, 16KB x2
//    LDS, 3 blocks/CU): measured <=43 us even WITH the atomic epilogue,
//    while BK=128/4-phase measured 75 us with it -> the 8-phase pipeline
//    hides latency better (more inter-block overlap, smaller LDS).
//  - EPILOGUE from R14 (plain single-writer stores to partial[row][32],
//    no atomics, no fence): R14 ablation proved the device-scope
//    atomicMin+threadfence path cost >=31 us (gram 75 -> <43.5 us,
//    K-loop byte-identical). finalize_kernel reduces the 32 slots/row.
// Only the K-loop differs from R14 -> the total delta is attributable.
// Slot coverage: row in tile t gets slot s>=t from the row-side of block
// (t,s) (incl. diagonal) and slot s<t from the col-side of block (s,t);
// each of the 32 slots written exactly once.
// ---------------------------------------------------------------------------
__global__ __launch_bounds__(256, 3) void gram_kernel(
    const uint16_t* __restrict__ Abf,
    const float4* __restrict__ meta,
    uint32_t* __restrict__ partial_all,     // [BN][NT] +inf-or-min d2 bits
    uint32_t* __restrict__ partial_larger)  // [BN][NT]
{
    __shared__ uint16_t Abuf[128 * 64];   // 16 KB, row stride 64 elem = 128 B
    __shared__ uint16_t Bbuf[128 * 64];   // 16 KB

    // triangular decode: blockIdx.x -> (bi, bj) with bi <= bj
    int t = blockIdx.x, bi = 0, rem = NT;
    while (t >= rem) { t -= rem; ++bi; --rem; }
    const int bj = bi + t;
    const bool offdiag = (bi != bj);
    const int rowBase = bi * 128;
    const int colBase = bj * 128;

    const int tid  = threadIdx.x;
    const int wave = tid >> 6;
    const int lane = tid & 63;
    const int wi   = wave >> 1;       // wave row in 2x2 grid (64-row halves)
    const int wj   = wave & 1;        // wave col (64-col halves)
    const int quad = lane >> 4;
    const int l15  = lane & 15;

    // Staging map (R0-proven): tile = 128 rows x 8 chunks of 16B. Thread
    // handles chunks l = tid + i*256 (i=0..3): row sr = l>>3, chunk sc = l&7,
    // LDS slot sp = sc ^ (sr&7)  (XOR-8 swizzle; 0 conflicts measured).
    int sr[4], sc[4], sp[4];
    #pragma unroll
    for (int i = 0; i < 4; ++i) {
        int l = tid + i * 256;
        sr[i] = l >> 3; sc[i] = l & 7; sp[i] = sc[i] ^ (sr[i] & 7);
    }

    float4v acc[4][4];
    #pragma unroll
    for (int i = 0; i < 4; ++i)
        #pragma unroll
        for (int j = 0; j < 4; ++j)
            acc[i][j] = (float4v){0.f, 0.f, 0.f, 0.f};

    for (int kt = 0; kt < DN / 64; ++kt) {           // 8 phases (NOT unrolled)
        const int k0 = kt * 64;
        __syncthreads();              // readers of previous phase done
        {
            // loads issued back-to-back (pipeline under counted vmcnt), then
            // ds_writes; nothing stays live past the next barrier (R4 lesson).
            uint4 st[4];
            #pragma unroll
            for (int i = 0; i < 4; ++i)
                st[i] = *(const uint4*)(Abf + (size_t)(rowBase + sr[i]) * DN + k0 + sc[i] * 8);
            #pragma unroll
            for (int i = 0; i < 4; ++i)
                *(uint4*)(Abuf + sr[i] * 64 + sp[i] * 8) = st[i];
            #pragma unroll
            for (int i = 0; i < 4; ++i)
                st[i] = *(const uint4*)(Abf + (size_t)(colBase + sr[i]) * DN + k0 + sc[i] * 8);
            #pragma unroll
            for (int i = 0; i < 4; ++i)
                *(uint4*)(Bbuf + sr[i] * 64 + sp[i] * 8) = st[i];
        }
        __syncthreads();              // LDS tiles visible

        #pragma unroll
        for (int kk = 0; kk < 2; ++kk) {             // 2 x K=32 sub-steps
            short8 af[4], bfr[4];
            #pragma unroll
            for (int mi = 0; mi < 4; ++mi) {
                int r = wi * 64 + mi * 16 + l15;
                int p = (kk * 4 + quad) ^ (r & 7);
                af[mi] = *(const short8*)(Abuf + r * 64 + p * 8);
            }
            #pragma unroll
            for (int mj = 0; mj < 4; ++mj) {
                int r = wj * 64 + mj * 16 + l15;
                int p = (kk * 4 + quad) ^ (r & 7);
                bfr[mj] = *(const short8*)(Bbuf + r * 64 + p * 8);
            }
            #pragma unroll
            for (int mi = 0; mi < 4; ++mi)
                #pragma unroll
                for (int mj = 0; mj < 4; ++mj)
                    acc[mi][mj] = __builtin_amdgcn_mfma_f32_16x16x32_bf16(
                        af[mi], bfr[mj], acc[mi][mj], 0, 0, 0);
        }
    }

    // ---- epilogue: squared distances, dual-side masked mins, PLAIN STORES ----
    const float INFF = __uint_as_float(INF_U);
    float4 mj_meta[4];
    #pragma unroll
    for (int mj = 0; mj < 4; ++mj)
        mj_meta[mj] = meta[colBase + wj * 64 + mj * 16 + l15];   // C/D col = lane&15

    float cAll[4], cLarger[4];
    #pragma unroll
    for (int mj = 0; mj < 4; ++mj) { cAll[mj] = INFF; cLarger[mj] = INFF; }

    #pragma unroll
    for (int mi = 0; mi < 4; ++mi) {
        #pragma unroll
        for (int r = 0; r < 4; ++r) {
            int row = rowBase + wi * 64 + mi * 16 + quad * 4 + r;  // C/D row = quad*4+reg
            float4 mim = meta[row];          // {sqn, dap, dap^2, label}
            uint32_t li = __float_as_uint(mim.w);
            float mAll = INFF, mLarger = INFF;
            #pragma unroll
            for (int mj = 0; mj < 4; ++mj) {
                float d2 = mim.x + mj_meta[mj].x - 2.0f * acc[mi][mj][r];
                d2 = d2 > 0.f ? d2 : 0.f;
                if (__float_as_uint(mj_meta[mj].w) != li) {
                    mAll = fminf(mAll, d2);
                    // reference: pd (euclidean) > d_ap (squared)  <=>  d2 > dap^2
                    if (d2 > mim.z) mLarger = fminf(mLarger, d2);
                    if (offdiag) {
                        cAll[mj] = fminf(cAll[mj], d2);
                        if (d2 > mj_meta[mj].z) cLarger[mj] = fminf(cLarger[mj], d2);
                    }
                }
            }
            // min across the 16 lanes of this quad (they share `row`, cover 64 cols)
            #pragma unroll
            for (int off = 1; off < 16; off <<= 1) {
                mAll    = fminf(mAll,    __shfl_xor(mAll, off));
                mLarger = fminf(mLarger, __shfl_xor(mLarger, off));
            }
            if (l15 == 0) {
                partial_all   [(size_t)row * NT + bj] = __float_as_uint(mAll);
                partial_larger[(size_t)row * NT + bj] = __float_as_uint(mLarger);
            }
        }
    }
    if (offdiag) {
        // col j = colBase + wj*64 + mj*16 + l15 is shared by the 4 quads
        #pragma unroll
        for (int mj = 0; mj < 4; ++mj) {
            float a0 = cAll[mj], l0 = cLarger[mj];
            a0 = fminf(a0, __shfl_xor(a0, 16)); l0 = fminf(l0, __shfl_xor(l0, 16));
            a0 = fminf(a0, __shfl_xor(a0, 32)); l0 = fminf(l0, __shfl_xor(l0, 32));
            if (quad == 0) {
                int col = colBase + wj * 64 + mj * 16 + l15;
                partial_all   [(size_t)col * NT + bi] = __float_as_uint(a0);
                partial_larger[(size_t)col * NT + bi] = __float_as_uint(l0);
            }
        }
    }
    // no fence, no counter — block just ends
}

// ---------------------------------------------------------------------------
// Kernel 3: per-row reduce of the 32 slots, select/sqrt/hinge, deterministic
// 16-way sum. 16 blocks x 256 threads, one row per thread.
// ---------------------------------------------------------------------------
__global__ __launch_bounds__(256) void finalize_kernel(
    const float4* __restrict__ meta,
    const uint32_t* __restrict__ partial_all,
    const uint32_t* __restrict__ partial_larger,
    float* __restrict__ psum,          // [16]
    uint32_t* __restrict__ done_count,
    float* __restrict__ out)
{
    const int tid = threadIdx.x;
    const int row = blockIdx.x * 256 + tid;
    const float INFF = __uint_as_float(INF_U);

    float mAll = INFF, mLarger = INFF;
    const uint4* pa = (const uint4*)(partial_all    + (size_t)row * NT);
    const uint4* pl = (const uint4*)(partial_larger + (size_t)row * NT);
    #pragma unroll
    for (int i = 0; i < 8; ++i) {
        uint4 a = pa[i], l = pl[i];
        mAll = fminf(mAll, fminf(fminf(__uint_as_float(a.x), __uint_as_float(a.y)),
                                 fminf(__uint_as_float(a.z), __uint_as_float(a.w))));
        mLarger = fminf(mLarger, fminf(fminf(__uint_as_float(l.x), __uint_as_float(l.y)),
                                       fminf(__uint_as_float(l.z), __uint_as_float(l.w))));
    }
    float dan2 = (__float_as_uint(mLarger) != INF_U) ? mLarger : mAll;
    float lv = meta[row].y - sqrtf(dan2) + MARGIN;
    float s = lv > 0.f ? lv : 0.f;

    #pragma unroll
    for (int off = 32; off; off >>= 1) s += __shfl_xor(s, off);
    __shared__ float wsum[4];
    if ((tid & 63) == 0) wsum[tid >> 6] = s;
    __syncthreads();

    __shared__ bool isLast;
    if (tid == 0) {
        psum[blockIdx.x] = wsum[0] + wsum[1] + wsum[2] + wsum[3];
        __threadfence();
        isLast = (atomicAdd(done_count, 1u) == 16 - 1);
    }
    __syncthreads();
    if (isLast && tid == 0) {
        __threadfence();
        float tot = 0.f;
        for (int b = 0; b < 16; ++b)
            tot += __hip_atomic_load(&psum[b], __ATOMIC_RELAXED, __HIP_MEMORY_SCOPE_AGENT);
        out[0] = tot * (1.0f / BN);
    }
}

// ---------------------------------------------------------------------------
extern "C" void kernel_launch(void* const* d_in, const int* in_sizes, int n_in,
                              void* d_out, int out_size, void* d_ws, size_t ws_size,
                              hipStream_t stream) {
    const float* anchor   = (const float*)d_in[0];
    const float* positive = (const float*)d_in[1];
    const int*   labels   = (const int*)d_in[2];
    float* out = (float*)d_out;

    // Workspace layout (~5.1 MB)
    uint8_t* ws = (uint8_t*)d_ws;
    uint16_t* Abf            = (uint16_t*)ws;                        // 4 MB bf16 anchor
    float4*   meta           = (float4*)(ws + (size_t)BN * DN * 2);  // 64 KB
    uint32_t* partial_all    = (uint32_t*)(meta + BN);               // 512 KB
    uint32_t* partial_larger = partial_all + (size_t)BN * NT;        // 512 KB
    float*    psum           = (float*)(partial_larger + (size_t)BN * NT); // 64 B
    uint32_t* done_count     = (uint32_t*)(psum + 16);               // 4 B

    prep_kernel<<<BN / 4, 256, 0, stream>>>(anchor, positive, labels, Abf, meta, done_count);
    gram_kernel<<<NBLK, 256, 0, stream>>>(Abf, meta, partial_all, partial_larger);
    finalize_kernel<<<16, 256, 0, stream>>>(meta, partial_all, partial_larger,
                                            psum, done_count, out);
}